// Round 8
// baseline (619.287 us; speedup 1.0000x reference)
//
#include <hip/hip_runtime.h>
#include <hip/hip_bf16.h>
#include <math.h>

// GAT: N=100000 nodes, E=1600000 edges (+N self loops), 3 layers.
// Inputs bf16 (runtime-detected flag kept). Intermediates bf16.
// CSR build: register-resident partition (block-private bucket regions,
// writes ~= data; u64-packed entries for nontemporal stores),
// XCD-local histogram from buckets, XCD-local scatter.
// GEMM: MFMA 16x16x32 bf16, fused BN/ELU on A-load, fused alpha-dot epilogue.

#define NNODES 100000
#define NEDGES 1600000
#define ENTOT  (NEDGES + NNODES)
#define NEG_SLOPE 0.2f
#define BN_EPS 1e-5f

#define NRANGE 8
#define RSIZE  (NNODES/NRANGE)     // 12500
#define BCAP   262144              // per-bucket capacity (mean 212.5k)
#define PBLK   2048                // partition blocks
#define NB2    32                  // scatter/hist blocks per range

typedef unsigned short u16;
typedef unsigned int u32;
typedef unsigned long long u64;
typedef __attribute__((ext_vector_type(8))) short short8;
typedef __attribute__((ext_vector_type(4))) float f32x4;

__device__ __forceinline__ float b2f(u16 u){ union{u32 i; float f;} v; v.i=((u32)u)<<16; return v.f; }
__device__ __forceinline__ u16 f2b(float x){ __hip_bfloat16 b=__float2bfloat16(x); return *(u16*)&b; }
__device__ __forceinline__ float ldf(const void* p, int i, int f){
  return f ? ((const float*)p)[i] : b2f(((const u16*)p)[i]);
}

// ---------------- dtype probe ----------------
__global__ void k_detect(const u16* __restrict__ x, int* __restrict__ flag){
  __shared__ int bad;
  if(threadIdx.x==0) bad=0;
  __syncthreads();
  int cnt=0;
  for(int i=threadIdx.x;i<4096;i+=256){
    u16 v = x[2*i];
    int ex = (v>>7)&0xff;
    if(ex==0xff || (ex==0 && (v&0x7fff)!=0)) cnt++;
  }
  atomicAdd(&bad,cnt);
  __syncthreads();
  if(threadIdx.x==0) flag[0] = (bad>4)?1:0;   // 1 = fp32, 0 = bf16
}

// ---------------- pass A: partition edges into 8 dst-range buckets ---------
// Edges held in registers; LDS atomicAdd gives exact block-local slot;
// one global atomic per (block,range); block-private regions -> clean writes.
__global__ __launch_bounds__(256) void k_part2(
    const int* __restrict__ ei, int* __restrict__ gptr, u64* __restrict__ bkt){
  __shared__ int lcnt[NRANGE], gbase[NRANGE];
  int t=threadIdx.x;
  if(t<NRANGE) lcnt[t]=0;
  __syncthreads();
  const int CH=(ENTOT+PBLK-1)/PBLK;   // 831
  int beg=blockIdx.x*CH, end=beg+CH; if(end>ENTOT) end=ENTOT;
  int nd[4], ns[4], nr[4], ne=0;
  for(int i=beg+t; i<end; i+=256){
    int d=(i<NEDGES)? ei[NEDGES+i] : (i-NEDGES);
    int s=(i<NEDGES)? ei[i] : d;
    nd[ne]=d; ns[ne]=s; ne++;
  }
  #pragma unroll 4
  for(int k=0;k<ne;k++) nr[k]=atomicAdd(&lcnt[nd[k]/RSIZE],1);
  __syncthreads();
  if(t<NRANGE) gbase[t]=atomicAdd(&gptr[t],lcnt[t]);
  __syncthreads();
  #pragma unroll 4
  for(int k=0;k<ne;k++){
    int r=nd[k]/RSIZE;
    u64 e = ((u64)(u32)nd[k]<<32) | (u32)ns[k];
    __builtin_nontemporal_store(e, &bkt[(size_t)r*BCAP + gbase[r] + nr[k]]);
  }
}

// ---------------- pass B0: XCD-local histogram from buckets ----------------
__global__ __launch_bounds__(256) void k_hist3(
    const u64* __restrict__ bkt, const int* __restrict__ gptr, int* __restrict__ cnt){
  int r = blockIdx.x & (NRANGE-1);
  int c = blockIdx.x >> 3;
  int n = gptr[r];
  int per=(n+NB2-1)/NB2;
  int beg=c*per, end=beg+per; if(end>n) end=n;
  const u64* bp = bkt + (size_t)r*BCAP;
  for(int i=beg+threadIdx.x;i<end;i+=256) atomicAdd(&cnt[(u32)(bp[i]>>32)],1);
}

// ---------------- prefix scan (row_ptr) ----------------
#define SCAN_M (NNODES+1)
#define SCAN_NB ((SCAN_M + 2047)/2048)

__global__ void k_scan_a(const int* __restrict__ cnt, int* __restrict__ bsum){
  __shared__ int red[256];
  int b=blockIdx.x, t=threadIdx.x;
  int base = b*2048 + t*8;
  int s=0;
  #pragma unroll
  for(int j=0;j<8;j++){ int idx=base+j; s += (idx<NNODES)? cnt[idx]:0; }
  red[t]=s; __syncthreads();
  for(int o=128;o>0;o>>=1){ if(t<o) red[t]+=red[t+o]; __syncthreads(); }
  if(t==0) bsum[b]=red[0];
}

__global__ void k_scan_b(int* bsum){
  if(threadIdx.x==0){
    int run=0;
    for(int i=0;i<SCAN_NB;i++){ int v=bsum[i]; bsum[i]=run; run+=v; }
  }
}

__global__ void k_scan_c(const int* __restrict__ cnt, const int* __restrict__ bsum,
                         int* __restrict__ row_ptr){
  __shared__ int lds[256];
  int b=blockIdx.x, t=threadIdx.x;
  int base=b*2048+t*8;
  int v[8]; int s=0;
  #pragma unroll
  for(int j=0;j<8;j++){ int idx=base+j; int x=(idx<NNODES)?cnt[idx]:0; v[j]=s; s+=x; }
  lds[t]=s; __syncthreads();
  for(int o=1;o<256;o<<=1){
    int other=0; if(t>=o) other=lds[t-o];
    __syncthreads();
    lds[t]+=other;
    __syncthreads();
  }
  int texcl = lds[t] - s;
  int off0 = bsum[b] + texcl;
  #pragma unroll
  for(int j=0;j<8;j++){ int idx=base+j; if(idx<SCAN_M) row_ptr[idx]=off0+v[j]; }
}

// ---------------- pass B1: per-range scatter (L2-resident windows) ---------
__global__ __launch_bounds__(256) void k_scatter3(
    const u64* __restrict__ bkt, const int* __restrict__ gptr,
    const int* __restrict__ row_ptr, int* __restrict__ nxt, int* __restrict__ col){
  int r = blockIdx.x & (NRANGE-1);
  int c = blockIdx.x >> 3;
  int n = gptr[r];
  int per = (n+NB2-1)/NB2;
  int beg = c*per, end = beg+per; if(end>n) end=n;
  const u64* bp = bkt + (size_t)r*BCAP;
  for(int i=beg+threadIdx.x;i<end;i+=256){
    u64 e=bp[i];
    int d=(int)(u32)(e>>32);
    int pos=row_ptr[d]+atomicAdd(&nxt[d],1);
    col[pos]=(int)(u32)e;
  }
}

// ---------------- MFMA GEMM + fused BN/ELU + alpha epilogue ----------------
template<int K, int OUTC, int HID, bool XEXT, bool BN>
__global__ __launch_bounds__(256) void k_gemm_mfma(
    const void* __restrict__ xin, const void* __restrict__ W,
    const void* __restrict__ avs, const void* __restrict__ avd,
    const float2* __restrict__ bnab,
    u16* __restrict__ hout, float* __restrict__ asrc, float* __restrict__ adst,
    const int* __restrict__ flagp)
{
  const int f = flagp[0];
  constexpr int KP = K+8;          // WT row stride (u16), 16B-aligned rows
  constexpr int RS = OUTC+8;       // HROW row stride (u16)
  constexpr int NT = OUTC/16;      // col tiles per wave
  constexpr int KQ = K/32;         // mfma K steps
  __shared__ __align__(16) u16 WT[OUTC*KP];
  __shared__ __align__(16) u16 HROW[4*16*RS];
  __shared__ float AVb[2*OUTC];
  __shared__ float2 BB[K];
  int t=threadIdx.x;
  const u16* Wu=(const u16*)W; const float* Wf=(const float*)W;
  for(int idx=t; idx<K*OUTC; idx+=256){
    int k=idx/OUTC, c=idx-k*OUTC;
    WT[c*KP+k] = f ? f2b(Wf[idx]) : Wu[idx];
  }
  for(int idx=t; idx<2*OUTC; idx+=256)
    AVb[idx] = (idx<OUTC)? ldf(avs,idx,f) : ldf(avd,idx-OUTC,f);
  if(BN) for(int idx=t; idx<K; idx+=256) BB[idx]=bnab[idx];
  __syncthreads();

  int wv=t>>6, lane=t&63;
  int m=lane&15, quad=lane>>4;
  int grow0 = blockIdx.x*64 + wv*16;
  int growA = grow0 + m;
  bool avalid = growA < NNODES;
  int growC = avalid ? growA : 0;

  f32x4 acc[NT] = {};
  #pragma unroll
  for(int kq=0;kq<KQ;kq++){
    int k0 = kq*32 + quad*8;
    union{ u32 u[4]; short8 s8; } A;
    if(XEXT && f==1){
      const float* xr=(const float*)xin + (size_t)growC*K + k0;
      float4 p=*(const float4*)xr, q=*(const float4*)(xr+4);
      A.u[0]=f2b(p.x)|((u32)f2b(p.y)<<16);
      A.u[1]=f2b(p.z)|((u32)f2b(p.w)<<16);
      A.u[2]=f2b(q.x)|((u32)f2b(q.y)<<16);
      A.u[3]=f2b(q.z)|((u32)f2b(q.w)<<16);
    } else {
      uint4 q=*(const uint4*)((const u16*)xin + (size_t)growC*K + k0);
      A.u[0]=q.x; A.u[1]=q.y; A.u[2]=q.z; A.u[3]=q.w;
    }
    if(BN){
      #pragma unroll
      for(int j=0;j<4;j++){
        float lo=b2f(A.u[j]&0xffff), hi=b2f(A.u[j]>>16);
        float2 c1=BB[k0+2*j], c2=BB[k0+2*j+1];
        lo=c1.x*lo+c1.y; lo = lo>0.f? lo : __expf(lo)-1.f;
        hi=c2.x*hi+c2.y; hi = hi>0.f? hi : __expf(hi)-1.f;
        A.u[j]=f2b(lo)|((u32)f2b(hi)<<16);
      }
    }
    #pragma unroll
    for(int nt=0;nt<NT;nt++){
      union{ uint4 q; short8 s8; } Bf;
      Bf.q = *(const uint4*)&WT[(nt*16+m)*KP + k0];
      acc[nt] = __builtin_amdgcn_mfma_f32_16x16x32_bf16(A.s8, Bf.s8, acc[nt], 0,0,0);
    }
  }
  u16* hr = &HROW[wv*16*RS];
  #pragma unroll
  for(int nt=0;nt<NT;nt++){
    #pragma unroll
    for(int reg=0;reg<4;reg++)
      hr[(quad*4+reg)*RS + nt*16+m] = f2b(acc[nt][reg]);
  }
  __syncthreads();
  {
    int row=lane&15, task=quad, head=task&1, sd=task>>1;
    float p=0.f;
    const u16* hrow=&hr[row*RS + head*HID];
    const float* av=&AVb[sd*OUTC + head*HID];
    #pragma unroll 8
    for(int c=0;c<HID;c++) p += b2f(hrow[c])*av[c];
    int grow=grow0+row;
    if(grow<NNODES){ (sd? adst:asrc)[grow*2+head]=p; }
  }
  {
    constexpr int CH8 = OUTC/8;
    for(int idx=lane; idx<16*CH8; idx+=64){
      int rr=idx/CH8, c8=idx-rr*CH8;
      int grow=grow0+rr;
      if(grow<NNODES)
        *(uint4*)(hout + (size_t)grow*OUTC + c8*8) = *(const uint4*)&hr[rr*RS + c8*8];
    }
  }
}

// ---------------- fused softmax + gather-aggregate -------------------------
template<int OUTC, bool FINAL>
__global__ __launch_bounds__(256) void k_aggf(
  const int* __restrict__ row_ptr, const int* __restrict__ col,
  const u16* __restrict__ hin, const float2* __restrict__ asrc2,
  const float2* __restrict__ adst2, const void* __restrict__ bias,
  u16* __restrict__ houtb, void* __restrict__ outv, const int* __restrict__ flagp)
{
  const int f = flagp[0];
  __shared__ float vbuf[4][80];
  int wave = threadIdx.x>>6, lane=threadIdx.x&63;
  int d = blockIdx.x*4 + wave;        // NNODES % 4 == 0
  int base=row_ptr[d], deg=row_ptr[d+1]-base;
  int slot=lane>>3, cg=lane&7;
  float2 adv = adst2[d];
  float acc0[4]={0.f,0.f,0.f,0.f}, acc1[4]={0.f,0.f,0.f,0.f}, accx[2]={0.f,0.f};
  float s0=0.f, s1=0.f;
  for(int j=0;j<deg;j+=8){
    int jj=j+slot;
    bool valid = jj<deg;
    int cs = col[base + (valid? jj : 0)];
    if(valid){
      float2 sv = asrc2[cs];
      float e0=sv.x+adv.x; e0 = e0>0.f? e0 : NEG_SLOPE*e0; e0=fminf(e0,60.f);
      float e1=sv.y+adv.y; e1 = e1>0.f? e1 : NEG_SLOPE*e1; e1=fminf(e1,60.f);
      float p0=__expf(e0), p1=__expf(e1);
      s0+=p0; s1+=p1;
      const u16* hp = hin + (size_t)cs*OUTC;
      ushort4 ha = *(const ushort4*)(hp + cg*4);
      ushort4 hb = *(const ushort4*)(hp + 32 + cg*4);
      float pa = p0;
      float pb = FINAL ? ((cg<2)? p0 : p1) : p1;   // FINAL: ch32..39 head0
      acc0[0]+=pa*b2f(ha.x); acc0[1]+=pa*b2f(ha.y); acc0[2]+=pa*b2f(ha.z); acc0[3]+=pa*b2f(ha.w);
      acc1[0]+=pb*b2f(hb.x); acc1[1]+=pb*b2f(hb.y); acc1[2]+=pb*b2f(hb.z); acc1[3]+=pb*b2f(hb.w);
      if(FINAL){
        ushort2 hc = *(const ushort2*)(hp + 64 + cg*2);
        accx[0]+=p1*b2f(hc.x); accx[1]+=p1*b2f(hc.y);
      }
    }
  }
  #pragma unroll
  for(int o=8;o<64;o<<=1){
    s0+=__shfl_xor(s0,o,64); s1+=__shfl_xor(s1,o,64);
    #pragma unroll
    for(int k=0;k<4;k++){ acc0[k]+=__shfl_xor(acc0[k],o,64); acc1[k]+=__shfl_xor(acc1[k],o,64); }
    if(FINAL){ accx[0]+=__shfl_xor(accx[0],o,64); accx[1]+=__shfl_xor(accx[1],o,64); }
  }
  float inv0 = s0>0.f?1.f/s0:0.f, inv1 = s1>0.f?1.f/s1:0.f;
  if(!FINAL){
    if(slot==0){
      ushort4 o0,o1;
      o0.x=f2b(acc0[0]*inv0 + ldf(bias,cg*4+0,f));
      o0.y=f2b(acc0[1]*inv0 + ldf(bias,cg*4+1,f));
      o0.z=f2b(acc0[2]*inv0 + ldf(bias,cg*4+2,f));
      o0.w=f2b(acc0[3]*inv0 + ldf(bias,cg*4+3,f));
      o1.x=f2b(acc1[0]*inv1 + ldf(bias,32+cg*4+0,f));
      o1.y=f2b(acc1[1]*inv1 + ldf(bias,32+cg*4+1,f));
      o1.z=f2b(acc1[2]*inv1 + ldf(bias,32+cg*4+2,f));
      o1.w=f2b(acc1[3]*inv1 + ldf(bias,32+cg*4+3,f));
      *(ushort4*)(houtb + (size_t)d*64 + cg*4)      = o0;
      *(ushort4*)(houtb + (size_t)d*64 + 32 + cg*4) = o1;
    }
  } else {
    if(slot==0){
      #pragma unroll
      for(int k=0;k<4;k++){
        int c  = cg*4+k;
        int c2 = 32+cg*4+k;
        vbuf[wave][c]  = acc0[k]*inv0;
        vbuf[wave][c2] = acc1[k]*((c2<40)?inv0:inv1);
      }
      vbuf[wave][64+cg*2]   = accx[0]*inv1;
      vbuf[wave][64+cg*2+1] = accx[1]*inv1;
    }
    __syncthreads();
    if(lane<40){
      float res = 0.5f*(vbuf[wave][lane] + vbuf[wave][40+lane]) + ldf(bias,lane,f);
      if(f) ((float*)outv)[(size_t)d*40+lane] = res;
      else  ((__hip_bfloat16*)outv)[(size_t)d*40+lane] = __float2bfloat16(res);
    }
  }
}

// ---------------- batch norm (stats + coefficient finalize) ---------------
__global__ __launch_bounds__(256) void k_bnstats(const u16* __restrict__ h, float* __restrict__ stats){
  __shared__ float red[4][128];
  int t=threadIdx.x; int c=t&63; int g=t>>6;
  float s=0.f,q=0.f;
  for(int r=blockIdx.x*4+g; r<NNODES; r+=gridDim.x*4){
    float v=b2f(h[(size_t)r*64+c]); s+=v; q+=v*v;
  }
  red[g][c]=s; red[g][64+c]=q;
  __syncthreads();
  if(t<128){
    float tot=red[0][t]+red[1][t]+red[2][t]+red[3][t];
    atomicAdd(&stats[t], tot);
  }
}

__global__ void k_bnfinal(const float* __restrict__ stats,
                          const void* __restrict__ gm, const void* __restrict__ bt,
                          float2* __restrict__ bnab, const int* __restrict__ flagp){
  const int f = flagp[0];
  int c=threadIdx.x;
  if(c>=64) return;
  float mu=stats[c]*(1.0f/NNODES);
  float var=stats[64+c]*(1.0f/NNODES)-mu*mu;
  var = var>0.f?var:0.f;
  float A = ldf(gm,c,f)*rsqrtf(var+BN_EPS);
  float B = ldf(bt,c,f) - A*mu;
  bnab[c]=make_float2(A,B);
}

extern "C" void kernel_launch(void* const* d_in, const int* in_sizes, int n_in,
                              void* d_out, int out_size, void* d_ws, size_t ws_size,
                              hipStream_t stream){
  const void* x  =d_in[0];
  const int* ei =(const int*)d_in[1];
  const void* W0 =d_in[2];  const void* as0=d_in[3];  const void* ad0=d_in[4];
  const void* b0 =d_in[5];  const void* g0 =d_in[6];  const void* bt0=d_in[7];
  const void* W1 =d_in[8];  const void* as1=d_in[9];  const void* ad1=d_in[10];
  const void* b1 =d_in[11]; const void* g1 =d_in[12]; const void* bt1=d_in[13];
  const void* W2 =d_in[14]; const void* as2=d_in[15]; const void* ad2=d_in[16];
  const void* b2 =d_in[17];

  char* ws=(char*)d_ws;
  size_t off=0;
  auto alloc=[&](size_t bytes)->void*{ void* p=ws+off; off+=(bytes+255)&~(size_t)255; return p; };
  int*    flag   =(int*)   alloc(256);
  int*    row_ptr=(int*)   alloc((size_t)(NNODES+1)*4);
  int*    cnt    =(int*)   alloc((size_t)NNODES*4);
  int*    colx   =(int*)   alloc((size_t)ENTOT*4);
  int*    bsum   =(int*)   alloc((size_t)SCAN_NB*4);
  int*    gptr   =(int*)   alloc(256);
  u64*    bkt    =(u64*)   alloc((size_t)NRANGE*BCAP*8);
  u16*    hA     =(u16*)   alloc((size_t)100032*80*2);
  u16*    hB0    =(u16*)   alloc((size_t)100032*64*2);
  u16*    hB1    =(u16*)   alloc((size_t)100032*64*2);
  float*  asrc   =(float*) alloc((size_t)NNODES*2*4);
  float*  adst   =(float*) alloc((size_t)NNODES*2*4);
  float*  stats  =(float*) alloc(128*4);
  float2* bnab   =(float2*)alloc(64*8);

  k_detect<<<1,256,0,stream>>>((const u16*)x, flag);

  // CSR by destination: partition -> hist(XCD-local) -> scan -> scatter
  (void)hipMemsetAsync(gptr,0,256,stream);
  k_part2  <<<PBLK,256,0,stream>>>(ei,gptr,bkt);
  (void)hipMemsetAsync(cnt,0,(size_t)NNODES*4,stream);
  k_hist3  <<<NRANGE*NB2,256,0,stream>>>(bkt,gptr,cnt);
  k_scan_a <<<SCAN_NB,256,0,stream>>>(cnt,bsum);
  k_scan_b <<<1,64,0,stream>>>(bsum);
  k_scan_c <<<SCAN_NB,256,0,stream>>>(cnt,bsum,row_ptr);
  (void)hipMemsetAsync(cnt,0,(size_t)NNODES*4,stream);
  k_scatter3<<<NRANGE*NB2,256,0,stream>>>(bkt,gptr,row_ptr,cnt,colx);

  int gG = (NNODES+63)/64;   // 1563
  int gN = NNODES/4;         // 25000
  // ---- layer 0 ----
  k_gemm_mfma<128,64,32,true ,false><<<gG,256,0,stream>>>(
      x,W0,as0,ad0,nullptr,hA,asrc,adst,flag);
  k_aggf<64,false><<<gN,256,0,stream>>>(row_ptr,colx,hA,
      (const float2*)asrc,(const float2*)adst,b0,hB0,nullptr,flag);
  (void)hipMemsetAsync(stats,0,512,stream);
  k_bnstats<<<256,256,0,stream>>>(hB0,stats);
  k_bnfinal<<<1,64,0,stream>>>(stats,g0,bt0,bnab,flag);
  // ---- layer 1 ----
  k_gemm_mfma<64,64,32,false,true ><<<gG,256,0,stream>>>(
      hB0,W1,as1,ad1,bnab,hA,asrc,adst,flag);
  k_aggf<64,false><<<gN,256,0,stream>>>(row_ptr,colx,hA,
      (const float2*)asrc,(const float2*)adst,b1,hB1,nullptr,flag);
  (void)hipMemsetAsync(stats,0,512,stream);
  k_bnstats<<<256,256,0,stream>>>(hB1,stats);
  k_bnfinal<<<1,64,0,stream>>>(stats,g1,bt1,bnab,flag);
  // ---- layer 2 (head mean -> d_out) ----
  k_gemm_mfma<64,80,40,false,true ><<<gG,256,0,stream>>>(
      hB1,W2,as2,ad2,bnab,hA,asrc,adst,flag);
  k_aggf<80,true ><<<gN,256,0,stream>>>(row_ptr,colx,hA,
      (const float2*)asrc,(const float2*)adst,b2,nullptr,d_out,flag);

  (void)in_sizes;(void)n_in;(void)out_size;(void)ws_size;
}

// Round 9
// 512.839 us; speedup vs baseline: 1.2076x; 1.2076x over previous
//
#include <hip/hip_runtime.h>
#include <hip/hip_bf16.h>
#include <math.h>

// GAT: N=100000 nodes, E=1600000 edges (+N self loops), 3 layers.
// Inputs bf16 (runtime-detected flag kept). Intermediates bf16.
// CSR build: atomic-free counting sort — partition to 8 dst-range buckets,
// per-(range,chunk) LDS histograms, node-wise chunk scan, LDS-offset scatter.
// (Global device-scope atomics cost ~40B RMW each at the coherence point —
//  1.7M of them was 70MB WRITE / 71us per pass. LDS atomics are free-ish.)
// GEMM: MFMA 16x16x32 bf16, fused BN/ELU on A-load, fused alpha-dot epilogue.

#define NNODES 100000
#define NEDGES 1600000
#define ENTOT  (NEDGES + NNODES)
#define NEG_SLOPE 0.2f
#define BN_EPS 1e-5f

#define NRANGE 8
#define RSIZE  (NNODES/NRANGE)     // 12500
#define BCAP   262144              // per-bucket capacity (mean 212.5k)
#define PBLK   2048                // partition blocks
#define NB2    32                  // chunks per range

typedef unsigned short u16;
typedef unsigned int u32;
typedef unsigned long long u64;
typedef __attribute__((ext_vector_type(8))) short short8;
typedef __attribute__((ext_vector_type(4))) float f32x4;

__device__ __forceinline__ float b2f(u16 u){ union{u32 i; float f;} v; v.i=((u32)u)<<16; return v.f; }
__device__ __forceinline__ u16 f2b(float x){ __hip_bfloat16 b=__float2bfloat16(x); return *(u16*)&b; }
__device__ __forceinline__ float ldf(const void* p, int i, int f){
  return f ? ((const float*)p)[i] : b2f(((const u16*)p)[i]);
}

// ---------------- dtype probe ----------------
__global__ void k_detect(const u16* __restrict__ x, int* __restrict__ flag){
  __shared__ int bad;
  if(threadIdx.x==0) bad=0;
  __syncthreads();
  int cnt=0;
  for(int i=threadIdx.x;i<4096;i+=256){
    u16 v = x[2*i];
    int ex = (v>>7)&0xff;
    if(ex==0xff || (ex==0 && (v&0x7fff)!=0)) cnt++;
  }
  atomicAdd(&bad,cnt);
  __syncthreads();
  if(threadIdx.x==0) flag[0] = (bad>4)?1:0;   // 1 = fp32, 0 = bf16
}

// ---------------- pass A: partition edges into 8 dst-range buckets ---------
__global__ __launch_bounds__(256) void k_part2(
    const int* __restrict__ ei, int* __restrict__ gptr, u64* __restrict__ bkt){
  __shared__ int lcnt[NRANGE], gbase[NRANGE];
  int t=threadIdx.x;
  if(t<NRANGE) lcnt[t]=0;
  __syncthreads();
  const int CH=(ENTOT+PBLK-1)/PBLK;   // 831
  int beg=blockIdx.x*CH, end=beg+CH; if(end>ENTOT) end=ENTOT;
  int nd[4], ns[4], nr[4], ne=0;
  for(int i=beg+t; i<end; i+=256){
    int d=(i<NEDGES)? ei[NEDGES+i] : (i-NEDGES);
    int s=(i<NEDGES)? ei[i] : d;
    nd[ne]=d; ns[ne]=s; ne++;
  }
  #pragma unroll 4
  for(int k=0;k<ne;k++) nr[k]=atomicAdd(&lcnt[nd[k]/RSIZE],1);
  __syncthreads();
  if(t<NRANGE) gbase[t]=atomicAdd(&gptr[t],lcnt[t]);
  __syncthreads();
  #pragma unroll 4
  for(int k=0;k<ne;k++){
    int r=nd[k]/RSIZE;
    u64 e = ((u64)(u32)nd[k]<<32) | (u32)ns[k];
    __builtin_nontemporal_store(e, &bkt[(size_t)r*BCAP + gbase[r] + nr[k]]);
  }
}

// ---------------- pass B0: per-(range,chunk) LDS histogram -----------------
__global__ __launch_bounds__(256) void k_hist4(
    const u64* __restrict__ bkt, const int* __restrict__ gptr, int* __restrict__ lhist){
  __shared__ int lh[RSIZE];
  int t=threadIdx.x;
  for(int i=t;i<RSIZE;i+=256) lh[i]=0;
  __syncthreads();
  int r = blockIdx.x & (NRANGE-1);
  int c = blockIdx.x >> 3;
  int lo = r*RSIZE;
  int n = gptr[r];
  int per=(n+NB2-1)/NB2;
  int beg=c*per, end=beg+per; if(end>n) end=n;
  const u64* bp = bkt + (size_t)r*BCAP;
  for(int i=beg+t;i<end;i+=256){
    int d=(int)(u32)(bp[i]>>32);
    atomicAdd(&lh[d-lo],1);
  }
  __syncthreads();
  int* out = lhist + (size_t)(r*NB2+c)*RSIZE;
  for(int i=t;i<RSIZE;i+=256) out[i]=lh[i];
}

// ---------------- node-wise chunk-scan: cnt + in-place exclusive scan ------
__global__ __launch_bounds__(256) void k_sumscan(int* __restrict__ lhist, int* __restrict__ cnt){
  int n = blockIdx.x*256 + threadIdx.x;
  if(n>=NNODES) return;
  int r = n/RSIZE, i = n - r*RSIZE;
  int* base = lhist + (size_t)r*NB2*RSIZE + i;
  int run=0;
  #pragma unroll 8
  for(int c=0;c<NB2;c++){
    int v = base[(size_t)c*RSIZE];
    base[(size_t)c*RSIZE] = run;
    run += v;
  }
  cnt[n]=run;
}

// ---------------- prefix scan (row_ptr) ----------------
#define SCAN_M (NNODES+1)
#define SCAN_NB ((SCAN_M + 2047)/2048)

__global__ void k_scan_a(const int* __restrict__ cnt, int* __restrict__ bsum){
  __shared__ int red[256];
  int b=blockIdx.x, t=threadIdx.x;
  int base = b*2048 + t*8;
  int s=0;
  #pragma unroll
  for(int j=0;j<8;j++){ int idx=base+j; s += (idx<NNODES)? cnt[idx]:0; }
  red[t]=s; __syncthreads();
  for(int o=128;o>0;o>>=1){ if(t<o) red[t]+=red[t+o]; __syncthreads(); }
  if(t==0) bsum[b]=red[0];
}

__global__ void k_scan_b(int* bsum){
  if(threadIdx.x==0){
    int run=0;
    for(int i=0;i<SCAN_NB;i++){ int v=bsum[i]; bsum[i]=run; run+=v; }
  }
}

__global__ void k_scan_c(const int* __restrict__ cnt, const int* __restrict__ bsum,
                         int* __restrict__ row_ptr){
  __shared__ int lds[256];
  int b=blockIdx.x, t=threadIdx.x;
  int base=b*2048+t*8;
  int v[8]; int s=0;
  #pragma unroll
  for(int j=0;j<8;j++){ int idx=base+j; int x=(idx<NNODES)?cnt[idx]:0; v[j]=s; s+=x; }
  lds[t]=s; __syncthreads();
  for(int o=1;o<256;o<<=1){
    int other=0; if(t>=o) other=lds[t-o];
    __syncthreads();
    lds[t]+=other;
    __syncthreads();
  }
  int texcl = lds[t] - s;
  int off0 = bsum[b] + texcl;
  #pragma unroll
  for(int j=0;j<8;j++){ int idx=base+j; if(idx<SCAN_M) row_ptr[idx]=off0+v[j]; }
}

// ---------------- pass B1: LDS-offset scatter (no global atomics) ----------
__global__ __launch_bounds__(256) void k_scatter4(
    const u64* __restrict__ bkt, const int* __restrict__ gptr,
    const int* __restrict__ row_ptr, const int* __restrict__ lhist,
    int* __restrict__ col){
  __shared__ int lofs[RSIZE];
  int t=threadIdx.x;
  int r = blockIdx.x & (NRANGE-1);
  int c = blockIdx.x >> 3;
  int lo = r*RSIZE;
  const int* cb = lhist + (size_t)(r*NB2+c)*RSIZE;
  for(int i=t;i<RSIZE;i+=256) lofs[i] = row_ptr[lo+i] + cb[i];
  __syncthreads();
  int n = gptr[r];
  int per=(n+NB2-1)/NB2;
  int beg=c*per, end=beg+per; if(end>n) end=n;
  const u64* bp = bkt + (size_t)r*BCAP;
  for(int i=beg+t;i<end;i+=256){
    u64 e=bp[i];
    int d=(int)(u32)(e>>32);
    int pos=atomicAdd(&lofs[d-lo],1);
    col[pos]=(int)(u32)e;
  }
}

// ---------------- MFMA GEMM + fused BN/ELU + alpha epilogue ----------------
template<int K, int OUTC, int HID, bool XEXT, bool BN>
__global__ __launch_bounds__(256) void k_gemm_mfma(
    const void* __restrict__ xin, const void* __restrict__ W,
    const void* __restrict__ avs, const void* __restrict__ avd,
    const float2* __restrict__ bnab,
    u16* __restrict__ hout, float* __restrict__ asrc, float* __restrict__ adst,
    const int* __restrict__ flagp)
{
  const int f = flagp[0];
  constexpr int KP = K+8;          // WT row stride (u16), 16B-aligned rows
  constexpr int RS = OUTC+8;       // HROW row stride (u16)
  constexpr int NT = OUTC/16;      // col tiles per wave
  constexpr int KQ = K/32;         // mfma K steps
  __shared__ __align__(16) u16 WT[OUTC*KP];
  __shared__ __align__(16) u16 HROW[4*16*RS];
  __shared__ float AVb[2*OUTC];
  __shared__ float2 BB[K];
  int t=threadIdx.x;
  const u16* Wu=(const u16*)W; const float* Wf=(const float*)W;
  for(int idx=t; idx<K*OUTC; idx+=256){
    int k=idx/OUTC, c=idx-k*OUTC;
    WT[c*KP+k] = f ? f2b(Wf[idx]) : Wu[idx];
  }
  for(int idx=t; idx<2*OUTC; idx+=256)
    AVb[idx] = (idx<OUTC)? ldf(avs,idx,f) : ldf(avd,idx-OUTC,f);
  if(BN) for(int idx=t; idx<K; idx+=256) BB[idx]=bnab[idx];
  __syncthreads();

  int wv=t>>6, lane=t&63;
  int m=lane&15, quad=lane>>4;
  int grow0 = blockIdx.x*64 + wv*16;
  int growA = grow0 + m;
  bool avalid = growA < NNODES;
  int growC = avalid ? growA : 0;

  f32x4 acc[NT] = {};
  #pragma unroll
  for(int kq=0;kq<KQ;kq++){
    int k0 = kq*32 + quad*8;
    union{ u32 u[4]; short8 s8; } A;
    if(XEXT && f==1){
      const float* xr=(const float*)xin + (size_t)growC*K + k0;
      float4 p=*(const float4*)xr, q=*(const float4*)(xr+4);
      A.u[0]=f2b(p.x)|((u32)f2b(p.y)<<16);
      A.u[1]=f2b(p.z)|((u32)f2b(p.w)<<16);
      A.u[2]=f2b(q.x)|((u32)f2b(q.y)<<16);
      A.u[3]=f2b(q.z)|((u32)f2b(q.w)<<16);
    } else {
      uint4 q=*(const uint4*)((const u16*)xin + (size_t)growC*K + k0);
      A.u[0]=q.x; A.u[1]=q.y; A.u[2]=q.z; A.u[3]=q.w;
    }
    if(BN){
      #pragma unroll
      for(int j=0;j<4;j++){
        float lo=b2f(A.u[j]&0xffff), hi=b2f(A.u[j]>>16);
        float2 c1=BB[k0+2*j], c2=BB[k0+2*j+1];
        lo=c1.x*lo+c1.y; lo = lo>0.f? lo : __expf(lo)-1.f;
        hi=c2.x*hi+c2.y; hi = hi>0.f? hi : __expf(hi)-1.f;
        A.u[j]=f2b(lo)|((u32)f2b(hi)<<16);
      }
    }
    #pragma unroll
    for(int nt=0;nt<NT;nt++){
      union{ uint4 q; short8 s8; } Bf;
      Bf.q = *(const uint4*)&WT[(nt*16+m)*KP + k0];
      acc[nt] = __builtin_amdgcn_mfma_f32_16x16x32_bf16(A.s8, Bf.s8, acc[nt], 0,0,0);
    }
  }
  u16* hr = &HROW[wv*16*RS];
  #pragma unroll
  for(int nt=0;nt<NT;nt++){
    #pragma unroll
    for(int reg=0;reg<4;reg++)
      hr[(quad*4+reg)*RS + nt*16+m] = f2b(acc[nt][reg]);
  }
  __syncthreads();
  {
    int row=lane&15, task=quad, head=task&1, sd=task>>1;
    float p=0.f;
    const u16* hrow=&hr[row*RS + head*HID];
    const float* av=&AVb[sd*OUTC + head*HID];
    #pragma unroll 8
    for(int c=0;c<HID;c++) p += b2f(hrow[c])*av[c];
    int grow=grow0+row;
    if(grow<NNODES){ (sd? adst:asrc)[grow*2+head]=p; }
  }
  {
    constexpr int CH8 = OUTC/8;
    for(int idx=lane; idx<16*CH8; idx+=64){
      int rr=idx/CH8, c8=idx-rr*CH8;
      int grow=grow0+rr;
      if(grow<NNODES)
        *(uint4*)(hout + (size_t)grow*OUTC + c8*8) = *(const uint4*)&hr[rr*RS + c8*8];
    }
  }
}

// ---------------- fused softmax + gather-aggregate -------------------------
template<int OUTC, bool FINAL>
__global__ __launch_bounds__(256) void k_aggf(
  const int* __restrict__ row_ptr, const int* __restrict__ col,
  const u16* __restrict__ hin, const float2* __restrict__ asrc2,
  const float2* __restrict__ adst2, const void* __restrict__ bias,
  u16* __restrict__ houtb, void* __restrict__ outv, const int* __restrict__ flagp)
{
  const int f = flagp[0];
  __shared__ float vbuf[4][80];
  int wave = threadIdx.x>>6, lane=threadIdx.x&63;
  int d = blockIdx.x*4 + wave;        // NNODES % 4 == 0
  int base=row_ptr[d], deg=row_ptr[d+1]-base;
  int slot=lane>>3, cg=lane&7;
  float2 adv = adst2[d];
  float acc0[4]={0.f,0.f,0.f,0.f}, acc1[4]={0.f,0.f,0.f,0.f}, accx[2]={0.f,0.f};
  float s0=0.f, s1=0.f;
  for(int j=0;j<deg;j+=8){
    int jj=j+slot;
    bool valid = jj<deg;
    int cs = col[base + (valid? jj : 0)];
    if(valid){
      float2 sv = asrc2[cs];
      float e0=sv.x+adv.x; e0 = e0>0.f? e0 : NEG_SLOPE*e0; e0=fminf(e0,60.f);
      float e1=sv.y+adv.y; e1 = e1>0.f? e1 : NEG_SLOPE*e1; e1=fminf(e1,60.f);
      float p0=__expf(e0), p1=__expf(e1);
      s0+=p0; s1+=p1;
      const u16* hp = hin + (size_t)cs*OUTC;
      ushort4 ha = *(const ushort4*)(hp + cg*4);
      ushort4 hb = *(const ushort4*)(hp + 32 + cg*4);
      float pa = p0;
      float pb = FINAL ? ((cg<2)? p0 : p1) : p1;   // FINAL: ch32..39 head0
      acc0[0]+=pa*b2f(ha.x); acc0[1]+=pa*b2f(ha.y); acc0[2]+=pa*b2f(ha.z); acc0[3]+=pa*b2f(ha.w);
      acc1[0]+=pb*b2f(hb.x); acc1[1]+=pb*b2f(hb.y); acc1[2]+=pb*b2f(hb.z); acc1[3]+=pb*b2f(hb.w);
      if(FINAL){
        ushort2 hc = *(const ushort2*)(hp + 64 + cg*2);
        accx[0]+=p1*b2f(hc.x); accx[1]+=p1*b2f(hc.y);
      }
    }
  }
  #pragma unroll
  for(int o=8;o<64;o<<=1){
    s0+=__shfl_xor(s0,o,64); s1+=__shfl_xor(s1,o,64);
    #pragma unroll
    for(int k=0;k<4;k++){ acc0[k]+=__shfl_xor(acc0[k],o,64); acc1[k]+=__shfl_xor(acc1[k],o,64); }
    if(FINAL){ accx[0]+=__shfl_xor(accx[0],o,64); accx[1]+=__shfl_xor(accx[1],o,64); }
  }
  float inv0 = s0>0.f?1.f/s0:0.f, inv1 = s1>0.f?1.f/s1:0.f;
  if(!FINAL){
    if(slot==0){
      ushort4 o0,o1;
      o0.x=f2b(acc0[0]*inv0 + ldf(bias,cg*4+0,f));
      o0.y=f2b(acc0[1]*inv0 + ldf(bias,cg*4+1,f));
      o0.z=f2b(acc0[2]*inv0 + ldf(bias,cg*4+2,f));
      o0.w=f2b(acc0[3]*inv0 + ldf(bias,cg*4+3,f));
      o1.x=f2b(acc1[0]*inv1 + ldf(bias,32+cg*4+0,f));
      o1.y=f2b(acc1[1]*inv1 + ldf(bias,32+cg*4+1,f));
      o1.z=f2b(acc1[2]*inv1 + ldf(bias,32+cg*4+2,f));
      o1.w=f2b(acc1[3]*inv1 + ldf(bias,32+cg*4+3,f));
      *(ushort4*)(houtb + (size_t)d*64 + cg*4)      = o0;
      *(ushort4*)(houtb + (size_t)d*64 + 32 + cg*4) = o1;
    }
  } else {
    if(slot==0){
      #pragma unroll
      for(int k=0;k<4;k++){
        int c  = cg*4+k;
        int c2 = 32+cg*4+k;
        vbuf[wave][c]  = acc0[k]*inv0;
        vbuf[wave][c2] = acc1[k]*((c2<40)?inv0:inv1);
      }
      vbuf[wave][64+cg*2]   = accx[0]*inv1;
      vbuf[wave][64+cg*2+1] = accx[1]*inv1;
    }
    __syncthreads();
    if(lane<40){
      float res = 0.5f*(vbuf[wave][lane] + vbuf[wave][40+lane]) + ldf(bias,lane,f);
      if(f) ((float*)outv)[(size_t)d*40+lane] = res;
      else  ((__hip_bfloat16*)outv)[(size_t)d*40+lane] = __float2bfloat16(res);
    }
  }
}

// ---------------- batch norm (stats + coefficient finalize) ---------------
__global__ __launch_bounds__(256) void k_bnstats(const u16* __restrict__ h, float* __restrict__ stats){
  __shared__ float red[4][128];
  int t=threadIdx.x; int c=t&63; int g=t>>6;
  float s=0.f,q=0.f;
  for(int r=blockIdx.x*4+g; r<NNODES; r+=gridDim.x*4){
    float v=b2f(h[(size_t)r*64+c]); s+=v; q+=v*v;
  }
  red[g][c]=s; red[g][64+c]=q;
  __syncthreads();
  if(t<128){
    float tot=red[0][t]+red[1][t]+red[2][t]+red[3][t];
    atomicAdd(&stats[t], tot);
  }
}

__global__ void k_bnfinal(const float* __restrict__ stats,
                          const void* __restrict__ gm, const void* __restrict__ bt,
                          float2* __restrict__ bnab, const int* __restrict__ flagp){
  const int f = flagp[0];
  int c=threadIdx.x;
  if(c>=64) return;
  float mu=stats[c]*(1.0f/NNODES);
  float var=stats[64+c]*(1.0f/NNODES)-mu*mu;
  var = var>0.f?var:0.f;
  float A = ldf(gm,c,f)*rsqrtf(var+BN_EPS);
  float B = ldf(bt,c,f) - A*mu;
  bnab[c]=make_float2(A,B);
}

extern "C" void kernel_launch(void* const* d_in, const int* in_sizes, int n_in,
                              void* d_out, int out_size, void* d_ws, size_t ws_size,
                              hipStream_t stream){
  const void* x  =d_in[0];
  const int* ei =(const int*)d_in[1];
  const void* W0 =d_in[2];  const void* as0=d_in[3];  const void* ad0=d_in[4];
  const void* b0 =d_in[5];  const void* g0 =d_in[6];  const void* bt0=d_in[7];
  const void* W1 =d_in[8];  const void* as1=d_in[9];  const void* ad1=d_in[10];
  const void* b1 =d_in[11]; const void* g1 =d_in[12]; const void* bt1=d_in[13];
  const void* W2 =d_in[14]; const void* as2=d_in[15]; const void* ad2=d_in[16];
  const void* b2 =d_in[17];

  char* ws=(char*)d_ws;
  size_t off=0;
  auto alloc=[&](size_t bytes)->void*{ void* p=ws+off; off+=(bytes+255)&~(size_t)255; return p; };
  int*    flag   =(int*)   alloc(256);
  int*    row_ptr=(int*)   alloc((size_t)(NNODES+1)*4);
  int*    cnt    =(int*)   alloc((size_t)NNODES*4);
  int*    colx   =(int*)   alloc((size_t)ENTOT*4);
  int*    bsum   =(int*)   alloc((size_t)SCAN_NB*4);
  int*    gptr   =(int*)   alloc(256);
  u64*    bkt    =(u64*)   alloc((size_t)NRANGE*BCAP*8);
  u16*    hA     =(u16*)   alloc((size_t)100032*80*2);   // aliased as lhist during CSR build
  u16*    hB0    =(u16*)   alloc((size_t)100032*64*2);
  u16*    hB1    =(u16*)   alloc((size_t)100032*64*2);
  float*  asrc   =(float*) alloc((size_t)NNODES*2*4);
  float*  adst   =(float*) alloc((size_t)NNODES*2*4);
  float*  stats  =(float*) alloc(128*4);
  float2* bnab   =(float2*)alloc(64*8);
  int*    lhist  =(int*)hA;   // 12.8 MB needed, hA is 16 MB; dead before gemm L0

  k_detect<<<1,256,0,stream>>>((const u16*)x, flag);

  // CSR: partition -> LDS hist -> chunk scan -> row_ptr scan -> LDS scatter
  (void)hipMemsetAsync(gptr,0,256,stream);
  k_part2  <<<PBLK,256,0,stream>>>(ei,gptr,bkt);
  k_hist4  <<<NRANGE*NB2,256,0,stream>>>(bkt,gptr,lhist);
  k_sumscan<<<(NNODES+255)/256,256,0,stream>>>(lhist,cnt);
  k_scan_a <<<SCAN_NB,256,0,stream>>>(cnt,bsum);
  k_scan_b <<<1,64,0,stream>>>(bsum);
  k_scan_c <<<SCAN_NB,256,0,stream>>>(cnt,bsum,row_ptr);
  k_scatter4<<<NRANGE*NB2,256,0,stream>>>(bkt,gptr,row_ptr,lhist,colx);

  int gG = (NNODES+63)/64;   // 1563
  int gN = NNODES/4;         // 25000
  // ---- layer 0 ----
  k_gemm_mfma<128,64,32,true ,false><<<gG,256,0,stream>>>(
      x,W0,as0,ad0,nullptr,hA,asrc,adst,flag);
  k_aggf<64,false><<<gN,256,0,stream>>>(row_ptr,colx,hA,
      (const float2*)asrc,(const float2*)adst,b0,hB0,nullptr,flag);
  (void)hipMemsetAsync(stats,0,512,stream);
  k_bnstats<<<256,256,0,stream>>>(hB0,stats);
  k_bnfinal<<<1,64,0,stream>>>(stats,g0,bt0,bnab,flag);
  // ---- layer 1 ----
  k_gemm_mfma<64,64,32,false,true ><<<gG,256,0,stream>>>(
      hB0,W1,as1,ad1,bnab,hA,asrc,adst,flag);
  k_aggf<64,false><<<gN,256,0,stream>>>(row_ptr,colx,hA,
      (const float2*)asrc,(const float2*)adst,b1,hB1,nullptr,flag);
  (void)hipMemsetAsync(stats,0,512,stream);
  k_bnstats<<<256,256,0,stream>>>(hB1,stats);
  k_bnfinal<<<1,64,0,stream>>>(stats,g1,bt1,bnab,flag);
  // ---- layer 2 (head mean -> d_out) ----
  k_gemm_mfma<64,80,40,false,true ><<<gG,256,0,stream>>>(
      hB1,W2,as2,ad2,bnab,hA,asrc,adst,flag);
  k_aggf<80,true ><<<gN,256,0,stream>>>(row_ptr,colx,hA,
      (const float2*)asrc,(const float2*)adst,b2,nullptr,d_out,flag);

  (void)in_sizes;(void)n_in;(void)out_size;(void)ws_size;
}

// Round 10
// 483.557 us; speedup vs baseline: 1.2807x; 1.0606x over previous
//
#include <hip/hip_runtime.h>
#include <hip/hip_bf16.h>
#include <math.h>

// GAT: N=100000 nodes, E=1600000 edges (+N self loops), 3 layers.
// Inputs bf16 (runtime-detected flag kept). Intermediates bf16.
// CSR build: atomic-free counting sort, u32-packed bucket entries
// (dst_local<<17 | src). Aggregation: one 16B gather per lane per edge,
// XCD-swizzled blocks so col/row_ptr slices are L2-local (scatter pinned them).

#define NNODES 100000
#define NEDGES 1600000
#define ENTOT  (NEDGES + NNODES)
#define NEG_SLOPE 0.2f
#define BN_EPS 1e-5f

#define NRANGE 8
#define RSIZE  (NNODES/NRANGE)     // 12500
#define BCAP   262144              // per-bucket capacity (mean 212.5k)
#define PBLK   2048                // partition blocks
#define NB2    32                  // chunks per range

typedef unsigned short u16;
typedef unsigned int u32;
typedef unsigned long long u64;
typedef __attribute__((ext_vector_type(8))) short short8;
typedef __attribute__((ext_vector_type(4))) float f32x4;

__device__ __forceinline__ float b2f(u16 u){ union{u32 i; float f;} v; v.i=((u32)u)<<16; return v.f; }
__device__ __forceinline__ u16 f2b(float x){ __hip_bfloat16 b=__float2bfloat16(x); return *(u16*)&b; }
__device__ __forceinline__ float ldf(const void* p, int i, int f){
  return f ? ((const float*)p)[i] : b2f(((const u16*)p)[i]);
}

// ---------------- dtype probe ----------------
__global__ void k_detect(const u16* __restrict__ x, int* __restrict__ flag){
  __shared__ int bad;
  if(threadIdx.x==0) bad=0;
  __syncthreads();
  int cnt=0;
  for(int i=threadIdx.x;i<4096;i+=256){
    u16 v = x[2*i];
    int ex = (v>>7)&0xff;
    if(ex==0xff || (ex==0 && (v&0x7fff)!=0)) cnt++;
  }
  atomicAdd(&bad,cnt);
  __syncthreads();
  if(threadIdx.x==0) flag[0] = (bad>4)?1:0;   // 1 = fp32, 0 = bf16
}

// ---------------- pass A: partition edges into 8 dst-range buckets ---------
__global__ __launch_bounds__(256) void k_part2(
    const int* __restrict__ ei, int* __restrict__ gptr, u32* __restrict__ bkt){
  __shared__ int lcnt[NRANGE], gbase[NRANGE];
  int t=threadIdx.x;
  if(t<NRANGE) lcnt[t]=0;
  __syncthreads();
  const int CH=(ENTOT+PBLK-1)/PBLK;   // 831
  int beg=blockIdx.x*CH, end=beg+CH; if(end>ENTOT) end=ENTOT;
  int nd[4], ns[4], nr[4], ne=0;
  for(int i=beg+t; i<end; i+=256){
    int d=(i<NEDGES)? ei[NEDGES+i] : (i-NEDGES);
    int s=(i<NEDGES)? ei[i] : d;
    nd[ne]=d; ns[ne]=s; ne++;
  }
  #pragma unroll 4
  for(int k=0;k<ne;k++) nr[k]=atomicAdd(&lcnt[nd[k]/RSIZE],1);
  __syncthreads();
  if(t<NRANGE) gbase[t]=atomicAdd(&gptr[t],lcnt[t]);
  __syncthreads();
  #pragma unroll 4
  for(int k=0;k<ne;k++){
    int r=nd[k]/RSIZE;
    u32 e = ((u32)(nd[k]-r*RSIZE)<<17) | (u32)ns[k];   // dst_local(14b)|src(17b)
    __builtin_nontemporal_store(e, &bkt[(size_t)r*BCAP + gbase[r] + nr[k]]);
  }
}

// ---------------- pass B0: per-(range,chunk) LDS histogram -----------------
__global__ __launch_bounds__(256) void k_hist4(
    const u32* __restrict__ bkt, const int* __restrict__ gptr, int* __restrict__ lhist){
  __shared__ int lh[RSIZE];
  int t=threadIdx.x;
  for(int i=t;i<RSIZE;i+=256) lh[i]=0;
  __syncthreads();
  int r = blockIdx.x & (NRANGE-1);
  int c = blockIdx.x >> 3;
  int n = gptr[r];
  int per=(n+NB2-1)/NB2;
  int beg=c*per, end=beg+per; if(end>n) end=n;
  const u32* bp = bkt + (size_t)r*BCAP;
  for(int i=beg+t;i<end;i+=256) atomicAdd(&lh[bp[i]>>17],1);
  __syncthreads();
  int* out = lhist + (size_t)(r*NB2+c)*RSIZE;
  for(int i=t;i<RSIZE;i+=256) out[i]=lh[i];
}

// ---------------- node-wise chunk-scan: cnt + in-place exclusive scan ------
__global__ __launch_bounds__(256) void k_sumscan(int* __restrict__ lhist, int* __restrict__ cnt){
  int n = blockIdx.x*256 + threadIdx.x;
  if(n>=NNODES) return;
  int r = n/RSIZE, i = n - r*RSIZE;
  int* base = lhist + (size_t)r*NB2*RSIZE + i;
  int run=0;
  #pragma unroll 8
  for(int c=0;c<NB2;c++){
    int v = base[(size_t)c*RSIZE];
    base[(size_t)c*RSIZE] = run;
    run += v;
  }
  cnt[n]=run;
}

// ---------------- prefix scan (row_ptr) ----------------
#define SCAN_M (NNODES+1)
#define SCAN_NB ((SCAN_M + 2047)/2048)

__global__ void k_scan_a(const int* __restrict__ cnt, int* __restrict__ bsum){
  __shared__ int red[256];
  int b=blockIdx.x, t=threadIdx.x;
  int base = b*2048 + t*8;
  int s=0;
  #pragma unroll
  for(int j=0;j<8;j++){ int idx=base+j; s += (idx<NNODES)? cnt[idx]:0; }
  red[t]=s; __syncthreads();
  for(int o=128;o>0;o>>=1){ if(t<o) red[t]+=red[t+o]; __syncthreads(); }
  if(t==0) bsum[b]=red[0];
}

__global__ void k_scan_b(int* bsum){
  if(threadIdx.x==0){
    int run=0;
    for(int i=0;i<SCAN_NB;i++){ int v=bsum[i]; bsum[i]=run; run+=v; }
  }
}

__global__ void k_scan_c(const int* __restrict__ cnt, const int* __restrict__ bsum,
                         int* __restrict__ row_ptr){
  __shared__ int lds[256];
  int b=blockIdx.x, t=threadIdx.x;
  int base=b*2048+t*8;
  int v[8]; int s=0;
  #pragma unroll
  for(int j=0;j<8;j++){ int idx=base+j; int x=(idx<NNODES)?cnt[idx]:0; v[j]=s; s+=x; }
  lds[t]=s; __syncthreads();
  for(int o=1;o<256;o<<=1){
    int other=0; if(t>=o) other=lds[t-o];
    __syncthreads();
    lds[t]+=other;
    __syncthreads();
  }
  int texcl = lds[t] - s;
  int off0 = bsum[b] + texcl;
  #pragma unroll
  for(int j=0;j<8;j++){ int idx=base+j; if(idx<SCAN_M) row_ptr[idx]=off0+v[j]; }
}

// ---------------- pass B1: LDS-offset scatter (no global atomics) ----------
__global__ __launch_bounds__(256) void k_scatter4(
    const u32* __restrict__ bkt, const int* __restrict__ gptr,
    const int* __restrict__ row_ptr, const int* __restrict__ lhist,
    int* __restrict__ col){
  __shared__ int lofs[RSIZE];
  int t=threadIdx.x;
  int r = blockIdx.x & (NRANGE-1);
  int c = blockIdx.x >> 3;
  int lo = r*RSIZE;
  const int* cb = lhist + (size_t)(r*NB2+c)*RSIZE;
  for(int i=t;i<RSIZE;i+=256) lofs[i] = row_ptr[lo+i] + cb[i];
  __syncthreads();
  int n = gptr[r];
  int per=(n+NB2-1)/NB2;
  int beg=c*per, end=beg+per; if(end>n) end=n;
  const u32* bp = bkt + (size_t)r*BCAP;
  for(int i=beg+t;i<end;i+=256){
    u32 e=bp[i];
    int pos=atomicAdd(&lofs[e>>17],1);
    col[pos]=(int)(e & 0x1FFFF);
  }
}

// ---------------- MFMA GEMM + fused BN/ELU + alpha epilogue ----------------
template<int K, int OUTC, int HID, bool XEXT, bool BN>
__global__ __launch_bounds__(256) void k_gemm_mfma(
    const void* __restrict__ xin, const void* __restrict__ W,
    const void* __restrict__ avs, const void* __restrict__ avd,
    const float2* __restrict__ bnab,
    u16* __restrict__ hout, float* __restrict__ asrc, float* __restrict__ adst,
    const int* __restrict__ flagp)
{
  const int f = flagp[0];
  constexpr int KP = K+8;          // WT row stride (u16), 16B-aligned rows
  constexpr int RS = OUTC+8;       // HROW row stride (u16)
  constexpr int NT = OUTC/16;      // col tiles per wave
  constexpr int KQ = K/32;         // mfma K steps
  __shared__ __align__(16) u16 WT[OUTC*KP];
  __shared__ __align__(16) u16 HROW[4*16*RS];
  __shared__ float AVb[2*OUTC];
  __shared__ float2 BB[K];
  int t=threadIdx.x;
  const u16* Wu=(const u16*)W; const float* Wf=(const float*)W;
  for(int i8=t*8; i8<K*OUTC; i8+=256*8){
    int k=i8/OUTC, c0=i8-k*OUTC;     // OUTC divisible by 8 -> row-local
    u16 w8[8];
    if(f){
      const float* wp=Wf+i8;
      float4 a=*(const float4*)wp, b=*(const float4*)(wp+4);
      w8[0]=f2b(a.x);w8[1]=f2b(a.y);w8[2]=f2b(a.z);w8[3]=f2b(a.w);
      w8[4]=f2b(b.x);w8[5]=f2b(b.y);w8[6]=f2b(b.z);w8[7]=f2b(b.w);
    } else {
      uint4 q=*(const uint4*)(Wu+i8);
      w8[0]=q.x&0xffff;w8[1]=q.x>>16;w8[2]=q.y&0xffff;w8[3]=q.y>>16;
      w8[4]=q.z&0xffff;w8[5]=q.z>>16;w8[6]=q.w&0xffff;w8[7]=q.w>>16;
    }
    #pragma unroll
    for(int u=0;u<8;u++) WT[(c0+u)*KP + k] = w8[u];
  }
  for(int idx=t; idx<2*OUTC; idx+=256)
    AVb[idx] = (idx<OUTC)? ldf(avs,idx,f) : ldf(avd,idx-OUTC,f);
  if(BN) for(int idx=t; idx<K; idx+=256) BB[idx]=bnab[idx];
  __syncthreads();

  int wv=t>>6, lane=t&63;
  int m=lane&15, quad=lane>>4;
  int grow0 = blockIdx.x*64 + wv*16;
  int growA = grow0 + m;
  bool avalid = growA < NNODES;
  int growC = avalid ? growA : 0;

  f32x4 acc[NT] = {};
  #pragma unroll
  for(int kq=0;kq<KQ;kq++){
    int k0 = kq*32 + quad*8;
    union{ u32 u[4]; short8 s8; } A;
    if(XEXT && f==1){
      const float* xr=(const float*)xin + (size_t)growC*K + k0;
      float4 p=*(const float4*)xr, q=*(const float4*)(xr+4);
      A.u[0]=f2b(p.x)|((u32)f2b(p.y)<<16);
      A.u[1]=f2b(p.z)|((u32)f2b(p.w)<<16);
      A.u[2]=f2b(q.x)|((u32)f2b(q.y)<<16);
      A.u[3]=f2b(q.z)|((u32)f2b(q.w)<<16);
    } else {
      uint4 q=*(const uint4*)((const u16*)xin + (size_t)growC*K + k0);
      A.u[0]=q.x; A.u[1]=q.y; A.u[2]=q.z; A.u[3]=q.w;
    }
    if(BN){
      #pragma unroll
      for(int j=0;j<4;j++){
        float lo=b2f(A.u[j]&0xffff), hi=b2f(A.u[j]>>16);
        float2 c1=BB[k0+2*j], c2=BB[k0+2*j+1];
        lo=c1.x*lo+c1.y; lo = lo>0.f? lo : __expf(lo)-1.f;
        hi=c2.x*hi+c2.y; hi = hi>0.f? hi : __expf(hi)-1.f;
        A.u[j]=f2b(lo)|((u32)f2b(hi)<<16);
      }
    }
    #pragma unroll
    for(int nt=0;nt<NT;nt++){
      union{ uint4 q; short8 s8; } Bf;
      Bf.q = *(const uint4*)&WT[(nt*16+m)*KP + k0];
      acc[nt] = __builtin_amdgcn_mfma_f32_16x16x32_bf16(A.s8, Bf.s8, acc[nt], 0,0,0);
    }
  }
  u16* hr = &HROW[wv*16*RS];
  #pragma unroll
  for(int nt=0;nt<NT;nt++){
    #pragma unroll
    for(int reg=0;reg<4;reg++)
      hr[(quad*4+reg)*RS + nt*16+m] = f2b(acc[nt][reg]);
  }
  __syncthreads();
  {
    int row=lane&15, task=quad, head=task&1, sd=task>>1;
    float p=0.f;
    const u16* hrow=&hr[row*RS + head*HID];
    const float* av=&AVb[sd*OUTC + head*HID];
    #pragma unroll 8
    for(int c=0;c<HID;c++) p += b2f(hrow[c])*av[c];
    int grow=grow0+row;
    if(grow<NNODES){ (sd? adst:asrc)[grow*2+head]=p; }
  }
  {
    constexpr int CH8 = OUTC/8;
    for(int idx=lane; idx<16*CH8; idx+=64){
      int rr=idx/CH8, c8=idx-rr*CH8;
      int grow=grow0+rr;
      if(grow<NNODES)
        *(uint4*)(hout + (size_t)grow*OUTC + c8*8) = *(const uint4*)&hr[rr*RS + c8*8];
    }
  }
}

// ---------------- fused softmax + gather-aggregate -------------------------
// One wave per dst node (XCD-swizzled: range = blockIdx%8 matches scatter4's
// L2 pinning of col/row_ptr). 8 edge slots x 8 lanes; lane cg owns channels
// [cg*8, cg*8+8) -> single 16B gather per lane per edge.
template<int OUTC, bool FINAL>
__global__ __launch_bounds__(256) void k_aggf(
  const int* __restrict__ row_ptr, const int* __restrict__ col,
  const u16* __restrict__ hin, const float2* __restrict__ asrc2,
  const float2* __restrict__ adst2, const void* __restrict__ bias,
  u16* __restrict__ houtb, void* __restrict__ outv, const int* __restrict__ flagp)
{
  const int f = flagp[0];
  __shared__ float vbuf[4][80];
  int wave = threadIdx.x>>6, lane=threadIdx.x&63;
  int rr = blockIdx.x & 7, jb = blockIdx.x >> 3;
  int d = rr*RSIZE + jb*4 + wave;     // 25000 blocks = 8 x 3125; RSIZE=3125*4
  int base=row_ptr[d], deg=row_ptr[d+1]-base;
  int slot=lane>>3, cg=lane&7;
  constexpr int HSPLIT = FINAL ? 5 : 4;   // cg<HSPLIT -> head0
  float2 adv = adst2[d];
  float acc[8]={0,0,0,0,0,0,0,0}, accx[2]={0.f,0.f};
  float s0=0.f, s1=0.f;
  for(int j=0;j<deg;j+=8){
    int jj=j+slot;
    bool valid = jj<deg;
    int cs = col[base + (valid? jj : 0)];
    if(valid){
      float2 sv = asrc2[cs];
      float e0=sv.x+adv.x; e0 = e0>0.f? e0 : NEG_SLOPE*e0; e0=fminf(e0,60.f);
      float e1=sv.y+adv.y; e1 = e1>0.f? e1 : NEG_SLOPE*e1; e1=fminf(e1,60.f);
      float p0=__expf(e0), p1=__expf(e1);
      s0+=p0; s1+=p1;
      const u16* hp = hin + (size_t)cs*OUTC;
      uint4 hq = *(const uint4*)(hp + cg*8);
      float p = (cg<HSPLIT)? p0 : p1;
      acc[0]+=p*b2f(hq.x&0xffff); acc[1]+=p*b2f(hq.x>>16);
      acc[2]+=p*b2f(hq.y&0xffff); acc[3]+=p*b2f(hq.y>>16);
      acc[4]+=p*b2f(hq.z&0xffff); acc[5]+=p*b2f(hq.z>>16);
      acc[6]+=p*b2f(hq.w&0xffff); acc[7]+=p*b2f(hq.w>>16);
      if(FINAL){
        ushort2 hc = *(const ushort2*)(hp + 64 + cg*2);
        accx[0]+=p1*b2f(hc.x); accx[1]+=p1*b2f(hc.y);
      }
    }
  }
  #pragma unroll
  for(int o=8;o<64;o<<=1){
    s0+=__shfl_xor(s0,o,64); s1+=__shfl_xor(s1,o,64);
    #pragma unroll
    for(int k=0;k<8;k++) acc[k]+=__shfl_xor(acc[k],o,64);
    if(FINAL){ accx[0]+=__shfl_xor(accx[0],o,64); accx[1]+=__shfl_xor(accx[1],o,64); }
  }
  float inv0 = s0>0.f?1.f/s0:0.f, inv1 = s1>0.f?1.f/s1:0.f;
  if(!FINAL){
    if(slot==0){
      float inv = (cg<4)? inv0 : inv1;
      u16 o8[8];
      #pragma unroll
      for(int k=0;k<8;k++) o8[k]=f2b(acc[k]*inv + ldf(bias,cg*8+k,f));
      uint4 ov;
      ov.x=(u32)o8[0]|((u32)o8[1]<<16); ov.y=(u32)o8[2]|((u32)o8[3]<<16);
      ov.z=(u32)o8[4]|((u32)o8[5]<<16); ov.w=(u32)o8[6]|((u32)o8[7]<<16);
      *(uint4*)(houtb + (size_t)d*64 + cg*8) = ov;
    }
  } else {
    if(slot==0){
      #pragma unroll
      for(int k=0;k<8;k++){
        int ch=cg*8+k;
        vbuf[wave][ch] = acc[k]*((ch<40)?inv0:inv1);
      }
      vbuf[wave][64+cg*2]   = accx[0]*inv1;
      vbuf[wave][64+cg*2+1] = accx[1]*inv1;
    }
    __syncthreads();
    if(lane<40){
      float res = 0.5f*(vbuf[wave][lane] + vbuf[wave][40+lane]) + ldf(bias,lane,f);
      if(f) ((float*)outv)[(size_t)d*40+lane] = res;
      else  ((__hip_bfloat16*)outv)[(size_t)d*40+lane] = __float2bfloat16(res);
    }
  }
}

// ---------------- batch norm (stats + coefficient finalize) ---------------
__global__ __launch_bounds__(256) void k_bnstats(const u16* __restrict__ h, float* __restrict__ stats){
  __shared__ float red[4][128];
  int t=threadIdx.x; int c=t&63; int g=t>>6;
  float s=0.f,q=0.f;
  for(int r=blockIdx.x*4+g; r<NNODES; r+=gridDim.x*4){
    float v=b2f(h[(size_t)r*64+c]); s+=v; q+=v*v;
  }
  red[g][c]=s; red[g][64+c]=q;
  __syncthreads();
  if(t<128){
    float tot=red[0][t]+red[1][t]+red[2][t]+red[3][t];
    atomicAdd(&stats[t], tot);
  }
}

__global__ void k_bnfinal(const float* __restrict__ stats,
                          const void* __restrict__ gm, const void* __restrict__ bt,
                          float2* __restrict__ bnab, const int* __restrict__ flagp){
  const int f = flagp[0];
  int c=threadIdx.x;
  if(c>=64) return;
  float mu=stats[c]*(1.0f/NNODES);
  float var=stats[64+c]*(1.0f/NNODES)-mu*mu;
  var = var>0.f?var:0.f;
  float A = ldf(gm,c,f)*rsqrtf(var+BN_EPS);
  float B = ldf(bt,c,f) - A*mu;
  bnab[c]=make_float2(A,B);
}

extern "C" void kernel_launch(void* const* d_in, const int* in_sizes, int n_in,
                              void* d_out, int out_size, void* d_ws, size_t ws_size,
                              hipStream_t stream){
  const void* x  =d_in[0];
  const int* ei =(const int*)d_in[1];
  const void* W0 =d_in[2];  const void* as0=d_in[3];  const void* ad0=d_in[4];
  const void* b0 =d_in[5];  const void* g0 =d_in[6];  const void* bt0=d_in[7];
  const void* W1 =d_in[8];  const void* as1=d_in[9];  const void* ad1=d_in[10];
  const void* b1 =d_in[11]; const void* g1 =d_in[12]; const void* bt1=d_in[13];
  const void* W2 =d_in[14]; const void* as2=d_in[15]; const void* ad2=d_in[16];
  const void* b2 =d_in[17];

  char* ws=(char*)d_ws;
  size_t off=0;
  auto alloc=[&](size_t bytes)->void*{ void* p=ws+off; off+=(bytes+255)&~(size_t)255; return p; };
  int*    flag   =(int*)   alloc(256);
  int*    row_ptr=(int*)   alloc((size_t)(NNODES+1)*4);
  int*    cnt    =(int*)   alloc((size_t)NNODES*4);
  int*    colx   =(int*)   alloc((size_t)ENTOT*4);
  int*    bsum   =(int*)   alloc((size_t)SCAN_NB*4);
  int*    gptr   =(int*)   alloc(256);
  u32*    bkt    =(u32*)   alloc((size_t)NRANGE*BCAP*4);
  u16*    hA     =(u16*)   alloc((size_t)100032*80*2);   // aliased as lhist during CSR build
  u16*    hB0    =(u16*)   alloc((size_t)100032*64*2);
  u16*    hB1    =(u16*)   alloc((size_t)100032*64*2);
  float*  asrc   =(float*) alloc((size_t)NNODES*2*4);
  float*  adst   =(float*) alloc((size_t)NNODES*2*4);
  float*  stats  =(float*) alloc(128*4);
  float2* bnab   =(float2*)alloc(64*8);
  int*    lhist  =(int*)hA;   // 12.8 MB needed, hA is 16 MB; dead before gemm L0

  k_detect<<<1,256,0,stream>>>((const u16*)x, flag);

  // CSR: partition -> LDS hist -> chunk scan -> row_ptr scan -> LDS scatter
  (void)hipMemsetAsync(gptr,0,256,stream);
  k_part2  <<<PBLK,256,0,stream>>>(ei,gptr,bkt);
  k_hist4  <<<NRANGE*NB2,256,0,stream>>>(bkt,gptr,lhist);
  k_sumscan<<<(NNODES+255)/256,256,0,stream>>>(lhist,cnt);
  k_scan_a <<<SCAN_NB,256,0,stream>>>(cnt,bsum);
  k_scan_b <<<1,64,0,stream>>>(bsum);
  k_scan_c <<<SCAN_NB,256,0,stream>>>(cnt,bsum,row_ptr);
  k_scatter4<<<NRANGE*NB2,256,0,stream>>>(bkt,gptr,row_ptr,lhist,colx);

  int gG = (NNODES+63)/64;   // 1563
  int gN = NNODES/4;         // 25000 (= 8 ranges x 3125)
  // ---- layer 0 ----
  k_gemm_mfma<128,64,32,true ,false><<<gG,256,0,stream>>>(
      x,W0,as0,ad0,nullptr,hA,asrc,adst,flag);
  k_aggf<64,false><<<gN,256,0,stream>>>(row_ptr,colx,hA,
      (const float2*)asrc,(const float2*)adst,b0,hB0,nullptr,flag);
  (void)hipMemsetAsync(stats,0,512,stream);
  k_bnstats<<<256,256,0,stream>>>(hB0,stats);
  k_bnfinal<<<1,64,0,stream>>>(stats,g0,bt0,bnab,flag);
  // ---- layer 1 ----
  k_gemm_mfma<64,64,32,false,true ><<<gG,256,0,stream>>>(
      hB0,W1,as1,ad1,bnab,hA,asrc,adst,flag);
  k_aggf<64,false><<<gN,256,0,stream>>>(row_ptr,colx,hA,
      (const float2*)asrc,(const float2*)adst,b1,hB1,nullptr,flag);
  (void)hipMemsetAsync(stats,0,512,stream);
  k_bnstats<<<256,256,0,stream>>>(hB1,stats);
  k_bnfinal<<<1,64,0,stream>>>(stats,g1,bt1,bnab,flag);
  // ---- layer 2 (head mean -> d_out) ----
  k_gemm_mfma<64,80,40,false,true ><<<gG,256,0,stream>>>(
      hB1,W2,as2,ad2,bnab,hA,asrc,adst,flag);
  k_aggf<80,true ><<<gN,256,0,stream>>>(row_ptr,colx,hA,
      (const float2*)asrc,(const float2*)adst,b2,nullptr,d_out,flag);

  (void)in_sizes;(void)n_in;(void)out_size;(void)ws_size;
}